// Round 1
// 2724.719 us; speedup vs baseline: 1.1312x; 1.1312x over previous
//
#include <hip/hip_runtime.h>

// ---------------------------------------------------------------------------
// 2-layer GRU, B=64 S=2048 IN=208 H=100 OUT=98, fp32.
// This version fuses the whole recurrent pipeline into ONE persistent kernel:
//   gemm_bias:  xg0 = seq @ w_ih_l0^T + b_ih_l0          (full-GPU GEMM)
//   gru_fused:  128 blocks.
//     blocks 0..63   : layer-0 scan for batch b, PLUS per-step matvec
//                      xg1_t = w_ih1 @ h0_t + b_ih1 -> global ring buffer
//     blocks 64..127 : layer-1 scan for batch b reading the ring, PLUS
//                      per-step out_t = w_out @ h1_t + b_out -> d_out
// Producer/consumer sync: agent-scope release/acquire progress flags,
// published every KPUB steps; layer-1 trails layer-0 by ~2*KPUB steps.
// This overlaps the two 1246us scans and deletes the xg1 and out GEMMs.
// ---------------------------------------------------------------------------

#define GB_BM 64
#define GB_BN 64
#define GB_BK 16

__global__ __launch_bounds__(256)
void gemm_bias(const float* __restrict__ A, const float* __restrict__ W,
               const float* __restrict__ bias, float* __restrict__ C,
               int Sc, long a_bs, long a_ss, long c_bs, long c_ss,
               int N, int K)
{
    // C[row, n] = sum_k A[row, k] * W[n, k] + bias[n]
    __shared__ float As[GB_BK][68];
    __shared__ float Bs[GB_BK][68];
    const int tid = threadIdx.x;
    const int m0 = blockIdx.x * GB_BM;
    const int n0 = blockIdx.y * GB_BN;

    const int lm = tid >> 2;          // 0..63
    const int lk = (tid & 3) << 2;    // 0,4,8,12
    const int row = m0 + lm;
    const float* arow = A + (long)(row / Sc) * a_bs + (long)(row % Sc) * a_ss;
    const int wrow = n0 + lm;
    const float* wrp = W + (long)wrow * K;
    const bool wv_ok = (wrow < N);

    const int tx = tid & 15;
    const int ty = tid >> 4;

    float acc[4][4] = {};

    for (int k0 = 0; k0 < K; k0 += GB_BK) {
        float4 av, bv;
        if (k0 + GB_BK <= K) {
            av = *(const float4*)(arow + k0 + lk);
            bv = wv_ok ? *(const float4*)(wrp + k0 + lk) : make_float4(0.f,0.f,0.f,0.f);
        } else {
            av = make_float4(0.f,0.f,0.f,0.f);
            bv = make_float4(0.f,0.f,0.f,0.f);
            const int kb = k0 + lk;
            if (kb + 0 < K) { av.x = arow[kb+0]; if (wv_ok) bv.x = wrp[kb+0]; }
            if (kb + 1 < K) { av.y = arow[kb+1]; if (wv_ok) bv.y = wrp[kb+1]; }
            if (kb + 2 < K) { av.z = arow[kb+2]; if (wv_ok) bv.z = wrp[kb+2]; }
            if (kb + 3 < K) { av.w = arow[kb+3]; if (wv_ok) bv.w = wrp[kb+3]; }
        }
        As[lk+0][lm] = av.x; As[lk+1][lm] = av.y; As[lk+2][lm] = av.z; As[lk+3][lm] = av.w;
        Bs[lk+0][lm] = bv.x; Bs[lk+1][lm] = bv.y; Bs[lk+2][lm] = bv.z; Bs[lk+3][lm] = bv.w;
        __syncthreads();
        #pragma unroll
        for (int kk = 0; kk < GB_BK; kk++) {
            float4 a  = *(const float4*)&As[kk][ty << 2];
            float4 bb = *(const float4*)&Bs[kk][tx << 2];
            float ar[4] = {a.x, a.y, a.z, a.w};
            float br[4] = {bb.x, bb.y, bb.z, bb.w};
            #pragma unroll
            for (int i = 0; i < 4; i++)
                #pragma unroll
                for (int j = 0; j < 4; j++)
                    acc[i][j] += ar[i] * br[j];
        }
        __syncthreads();
    }

    #pragma unroll
    for (int i = 0; i < 4; i++) {
        const int r = m0 + (ty << 2) + i;
        float* crow = C + (long)(r / Sc) * c_bs + (long)(r % Sc) * c_ss;
        #pragma unroll
        for (int j = 0; j < 4; j++) {
            const int col = n0 + (tx << 2) + j;
            if (col < N) crow[col] = acc[i][j] + bias[col];
        }
    }
}

// ---------------------------------------------------------------------------
// Fused persistent 2-layer scan.
// ---------------------------------------------------------------------------

#define RING_W 256   // ring depth in timesteps (power of 2), per batch
#define KPUB   16    // flag publish / wait granularity in timesteps

__device__ __forceinline__ float fsig(float x)  { return 1.f / (1.f + __expf(-x)); }
__device__ __forceinline__ float ftanh(float x) { return 1.f - 2.f / (1.f + __expf(2.f * x)); }

__global__ __launch_bounds__(640, 1)
void gru_fused(const float* __restrict__ xg0,      // (B,S,300) precomputed
               const float* __restrict__ w_hh0, const float* __restrict__ b_hh0,
               const float* __restrict__ w_ih1, const float* __restrict__ b_ih1,
               const float* __restrict__ w_hh1, const float* __restrict__ b_hh1,
               const float* __restrict__ w_out, const float* __restrict__ b_out,
               const float* __restrict__ h_init, // (2,B,100)
               float* __restrict__ ring,          // (B, RING_W, 300)
               int* prog0, int* cons1,            // 64*32 ints each (128B-padded)
               float* __restrict__ out,           // (B,S,98)
               int S)
{
    __shared__ __align__(16) float hs[100];
    __shared__ float hg_lds[300];
    __shared__ float xg_lds[300];

    const int tid   = threadIdx.x;
    const int layer = blockIdx.x >> 6;   // 0 or 1
    const int b     = blockIdx.x & 63;
    const int half  = tid & 1;
    const int g     = tid >> 1;          // dot index (gate or out-row)
    const bool dot  = (tid < 600);
    const bool even = dot && (half == 0);

    int* myprog = prog0 + b * 32;
    int* mycons = cons1 + b * 32;

    // --- weights in registers ---------------------------------------------
    // wv : w_hh row-half (both layers, dot threads)
    // wv2: layer0 -> w_ih1 row-half (dot threads, 300 gates)
    //      layer1 -> w_out row-half (tid<196, 98 outputs)
    float4 wv[13], wv2[13];
    float bhh = 0.f, bias2 = 0.f;
    const float* w_hh = layer ? w_hh1 : w_hh0;
    if (dot) {
        const float* p = w_hh + g * 100 + half * 48;   // 16B aligned
        #pragma unroll
        for (int i = 0; i < 13; i++) wv[i] = *(const float4*)(p + 4 * i);
        if (!half) wv[12] = make_float4(0.f, 0.f, 0.f, 0.f);  // half0: k<48 only
    }
    const bool has2 = layer == 0 ? dot : (tid < 196);
    if (has2) {
        const float* W2 = layer ? w_out : w_ih1;
        const float* p = W2 + g * 100 + half * 48;
        #pragma unroll
        for (int i = 0; i < 13; i++) wv2[i] = *(const float4*)(p + 4 * i);
        if (!half) wv2[12] = make_float4(0.f, 0.f, 0.f, 0.f);
    }
    if (even) bhh = (layer ? b_hh1 : b_hh0)[g];
    if (has2 && !half) bias2 = (layer ? b_out : b_ih1)[g];

    float hcur = 0.f;
    if (tid < 100) {
        hcur = h_init[layer * 6400 + b * 100 + tid];
        hs[tid] = hcur;
    }

    float* ringb = ring + (size_t)b * RING_W * 300;

    if (layer == 0) {
        // =================== LAYER 0 (producer) ===========================
        const float* xgb = xg0 + (size_t)b * S * 300;
        float xnext = 0.f;
        if (even) xnext = xgb[g];                       // prefetch t=0
        __syncthreads();

        for (int t = 0; t < S; t++) {
            const float xcur = xnext;
            if (even && t + 1 < S) xnext = xgb[(size_t)(t + 1) * 300 + g];

            // hg_t = w_hh0 . h_{t-1}
            float tot = 0.f;
            if (dot) {
                const float4* hs4 = (const float4*)hs;
                const int base = half * 12;
                float a0 = 0.f, a1 = 0.f, a2 = 0.f, a3 = 0.f;
                #pragma unroll
                for (int i = 0; i < 13; i++) {
                    const float4 h4 = hs4[base + i];
                    const float4 w = wv[i];
                    a0 += w.x * h4.x; a1 += w.y * h4.y;
                    a2 += w.z * h4.z; a3 += w.w * h4.w;
                }
                tot = (a0 + a2) + (a1 + a3);
                tot += __shfl_down(tot, 1);             // even lane has full dot
            }
            if (even) { hg_lds[g] = tot + bhh; xg_lds[g] = xcur; }
            __syncthreads();   // sync1 -- also drains ring stores of iter t-1

            if (tid == 0 && t > 0 && (t % KPUB) == 0) {
                // publish: ring steps 0..t-1 are globally visible after this
                __hip_atomic_store(myprog, t, __ATOMIC_RELEASE, __HIP_MEMORY_SCOPE_AGENT);
                // back-pressure (practically never spins: lag << RING_W)
                const int need = t + KPUB - RING_W;
                if (need > 0) {
                    while (__hip_atomic_load(mycons, __ATOMIC_ACQUIRE, __HIP_MEMORY_SCOPE_AGENT) < need)
                        __builtin_amdgcn_s_sleep(2);
                }
            }
            if (tid < 100) {
                const float xr = xg_lds[tid], xz = xg_lds[100 + tid], xn = xg_lds[200 + tid];
                const float hr = hg_lds[tid], hz = hg_lds[100 + tid], hn = hg_lds[200 + tid];
                const float r = fsig(xr + hr);
                const float z = fsig(xz + hz);
                const float n = ftanh(xn + r * hn);
                hcur = (1.f - z) * n + z * hcur;
                hs[tid] = hcur;
            }
            __syncthreads();   // sync2 -- hs now holds h_t

            // xg1_t = w_ih1 . h_t  -> ring slot t (off the critical chain)
            if (dot) {
                const float4* hs4 = (const float4*)hs;
                const int base = half * 12;
                float a0 = 0.f, a1 = 0.f, a2 = 0.f, a3 = 0.f;
                #pragma unroll
                for (int i = 0; i < 13; i++) {
                    const float4 h4 = hs4[base + i];
                    const float4 w = wv2[i];
                    a0 += w.x * h4.x; a1 += w.y * h4.y;
                    a2 += w.z * h4.z; a3 += w.w * h4.w;
                }
                float tot2 = (a0 + a2) + (a1 + a3);
                tot2 += __shfl_down(tot2, 1);
                if (!half) ringb[(size_t)(t & (RING_W - 1)) * 300 + g] = tot2 + bias2;
            }
        }
        __syncthreads();       // drain final ring stores
        if (tid == 0)
            __hip_atomic_store(myprog, S, __ATOMIC_RELEASE, __HIP_MEMORY_SCOPE_AGENT);

    } else {
        // =================== LAYER 1 (consumer) ===========================
        float xnext = 0.f;
        if (tid == 0) {
            const int tgt0 = (KPUB + 1 < S) ? KPUB + 1 : S;  // covers steps 0..KPUB
            while (__hip_atomic_load(myprog, __ATOMIC_ACQUIRE, __HIP_MEMORY_SCOPE_AGENT) < tgt0)
                __builtin_amdgcn_s_sleep(2);
        }
        __syncthreads();
        if (even) xnext = ringb[g];                     // prefetch t=0

        for (int t = 0; t < S; t++) {
            const float xcur = xnext;
            if (even && t + 1 < S)
                xnext = ringb[(size_t)((t + 1) & (RING_W - 1)) * 300 + g];

            // hg_t = w_hh1 . h_{t-1}
            float tot = 0.f;
            if (dot) {
                const float4* hs4 = (const float4*)hs;
                const int base = half * 12;
                float a0 = 0.f, a1 = 0.f, a2 = 0.f, a3 = 0.f;
                #pragma unroll
                for (int i = 0; i < 13; i++) {
                    const float4 h4 = hs4[base + i];
                    const float4 w = wv[i];
                    a0 += w.x * h4.x; a1 += w.y * h4.y;
                    a2 += w.z * h4.z; a3 += w.w * h4.w;
                }
                tot = (a0 + a2) + (a1 + a3);
                tot += __shfl_down(tot, 1);
            }
            if (even) { hg_lds[g] = tot + bhh; xg_lds[g] = xcur; }
            __syncthreads();   // sync1

            if (tid == 0) {
                if (t > 0 && (t % KPUB) == 0)   // reads of ring steps <= t done
                    __hip_atomic_store(mycons, t, __ATOMIC_RELEASE, __HIP_MEMORY_SCOPE_AGENT);
                if (((t + 1) % KPUB) == 0) {
                    // next window [t+1, t+1+KPUB): consumes + prefetches up to t+1+KPUB
                    int tgt = t + 1 + KPUB + 1;
                    if (tgt > S) tgt = S;
                    while (__hip_atomic_load(myprog, __ATOMIC_ACQUIRE, __HIP_MEMORY_SCOPE_AGENT) < tgt)
                        __builtin_amdgcn_s_sleep(2);
                }
            }
            if (tid < 100) {
                const float xr = xg_lds[tid], xz = xg_lds[100 + tid], xn = xg_lds[200 + tid];
                const float hr = hg_lds[tid], hz = hg_lds[100 + tid], hn = hg_lds[200 + tid];
                const float r = fsig(xr + hr);
                const float z = fsig(xz + hz);
                const float n = ftanh(xn + r * hn);
                hcur = (1.f - z) * n + z * hcur;
                hs[tid] = hcur;
            }
            __syncthreads();   // sync2 -- hs now holds h_t

            // out_t = w_out . h_t + b_out  -> d_out
            if (tid < 196) {
                const float4* hs4 = (const float4*)hs;
                const int base = half * 12;
                float a0 = 0.f, a1 = 0.f, a2 = 0.f, a3 = 0.f;
                #pragma unroll
                for (int i = 0; i < 13; i++) {
                    const float4 h4 = hs4[base + i];
                    const float4 w = wv2[i];
                    a0 += w.x * h4.x; a1 += w.y * h4.y;
                    a2 += w.z * h4.z; a3 += w.w * h4.w;
                }
                float tot2 = (a0 + a2) + (a1 + a3);
                tot2 += __shfl_down(tot2, 1);
                if (!half) out[((size_t)b * S + t) * 98 + g] = tot2 + bias2;
            }
        }
    }
}

// ---------------------------------------------------------------------------

extern "C" void kernel_launch(void* const* d_in, const int* in_sizes, int n_in,
                              void* d_out, int out_size, void* d_ws, size_t ws_size,
                              hipStream_t stream)
{
    const float* seq    = (const float*)d_in[0];
    const float* h0     = (const float*)d_in[1];   // (2, 64, 100)
    const float* w_ih0  = (const float*)d_in[2];   // (300, 208)
    const float* w_hh0  = (const float*)d_in[3];   // (300, 100)
    const float* b_ih0  = (const float*)d_in[4];
    const float* b_hh0  = (const float*)d_in[5];
    const float* w_ih1  = (const float*)d_in[6];   // (300, 100)
    const float* w_hh1  = (const float*)d_in[7];
    const float* b_ih1  = (const float*)d_in[8];
    const float* b_hh1  = (const float*)d_in[9];
    const float* w_out  = (const float*)d_in[10];  // (98, 100)
    const float* b_out  = (const float*)d_in[11];
    float* out = (float*)d_out;

    const int B = 64, S = 2048, IN = 208, G = 300;

    // workspace layout: flags (2 * 64*32 ints) | xg0 (B,S,300) | ring (B,RING_W,300)
    int* prog0 = (int*)d_ws;
    int* cons1 = prog0 + 64 * 32;
    float* xg0 = (float*)(cons1 + 64 * 32);
    float* ringbuf = xg0 + (size_t)B * S * G;

    hipMemsetAsync(d_ws, 0, 2 * 64 * 32 * sizeof(int), stream);

    // xg0 = seq @ w_ih0^T + b_ih0   (full S in one pass)
    const dim3 blk(256);
    const dim3 gX((B * S) / GB_BM, (G + GB_BN - 1) / GB_BN);   // (2048, 5)
    gemm_bias<<<gX, blk, 0, stream>>>(seq, w_ih0, b_ih0, xg0,
                                      S, (long)S * IN, (long)IN,
                                      (long)S * G, (long)G, G, IN);

    // fused persistent 2-layer scan + out projection
    gru_fused<<<dim3(128), dim3(640), 0, stream>>>(
        xg0, w_hh0, b_hh0, w_ih1, b_ih1, w_hh1, b_hh1, w_out, b_out,
        h0, ringbuf, prog0, cons1, out, S);
}